// Round 11
// baseline (220.328 us; speedup 1.0000x reference)
//
#include <hip/hip_runtime.h>
#include <hip/hip_bf16.h>
#include <stdint.h>

#define BB 64
#define NN 196
#define D1c 512
#define D2c 2048
#define HHc 512
#define MM (BB*NN)   // 12544

typedef __attribute__((ext_vector_type(8))) short bf16x8;
typedef __attribute__((ext_vector_type(4))) float f32x4;

__device__ inline ushort f2bf(float f){
  uint32_t u = __float_as_uint(f);
  u += 0x7fff + ((u >> 16) & 1);   // RNE
  return (ushort)(u >> 16);
}
__device__ inline uint32_t cvtpk(float lo, float hi){
  uint32_t r;
  asm("v_cvt_pk_bf16_f32 %0, %1, %2" : "=v"(r) : "v"(lo), "v"(hi));
  return r;
}

// ---- W2 [2048][512] f32  ->  w2t [512][2048] bf16 (row-major transposed) ----
__global__ __launch_bounds__(256) void w2t_kernel(const float* __restrict__ W2,
                                                  ushort* __restrict__ w2t){
  __shared__ float tile[64][65];
  const int kt = blockIdx.x;
  const int ht = blockIdx.y;
  const int t = threadIdx.x;
  const int tr = t >> 4;
  const int tc = (t & 15) * 4;
  #pragma unroll
  for (int p = 0; p < 4; ++p){
    int k = p*16 + tr;
    float4 v = *(const float4*)(W2 + (size_t)(kt*64 + k)*HHc + ht*64 + tc);
    tile[k][tc] = v.x; tile[k][tc+1] = v.y; tile[k][tc+2] = v.z; tile[k][tc+3] = v.w;
  }
  __syncthreads();
  #pragma unroll
  for (int p = 0; p < 4; ++p){
    int h = p*16 + tr;
    ushort4 o;
    o.x = f2bf(tile[tc  ][h]);
    o.y = f2bf(tile[tc+1][h]);
    o.z = f2bf(tile[tc+2][h]);
    o.w = f2bf(tile[tc+3][h]);
    *(ushort4*)(w2t + (size_t)(ht*64 + h)*D2c + kt*64 + tc) = o;
  }
}

// ---- enc1 = input1 @ W1 + b1   [64][512] f32 ----
__global__ __launch_bounds__(128) void enc1_kernel(const float* __restrict__ in1,
                                                   const float* __restrict__ W1,
                                                   const float* __restrict__ b1,
                                                   float* __restrict__ enc1){
  __shared__ float s1[D1c];
  const int b = blockIdx.x;
  const int ht = blockIdx.y;
  const int t = threadIdx.x;
  ((float4*)s1)[t] = ((const float4*)(in1 + (size_t)b*D1c))[t];
  __syncthreads();
  const int h = ht*128 + t;
  float acc = b1[h];
  #pragma unroll 8
  for (int d = 0; d < D1c; ++d)
    acc += s1[d] * W1[(size_t)d*HHc + h];
  enc1[b*HHc + h] = acc;
}

// ======== shared macros for score_gemm + diagnostics ========
#define GEMM_PREAMBLE(scoresArg)                                             \
  __shared__ ushort As[2][128*64];                                           \
  __shared__ ushort Bs[2][256*64];                                           \
  const int t = threadIdx.x;                                                 \
  const int p   = blockIdx.x;                                                \
  const int xcd = p & 7;                                                     \
  const int lg  = (xcd < 4 ? xcd*25 : 100 + (xcd-4)*24) + (p >> 3);          \
  const int h0  = (lg & 1) * 256;                                            \
  const int m0  = (lg >> 1) * 128;                                           \
  const int wave = t >> 6, lane = t & 63;                                    \
  const int wm = wave >> 2, whh = wave & 3;                                  \
  const int l15 = lane & 15, l4 = lane >> 4;                                 \
  const int rA = wave*16 + l4;                                               \
  const float* aBase = in2 + (size_t)(m0 + rA)*D2c + l15*4;                  \
  const int acw  = l15 >> 1;                                                 \
  const int apar = (l15 & 1) * 4;                                            \
  const int bl_r = lane >> 3;                                                \
  const int bl_c = (lane & 7) ^ bl_r;                                        \
  float b2v[4], wfv[4];                                                      \
  _Pragma("unroll")                                                          \
  for (int hf = 0; hf < 4; ++hf){                                            \
    int hc = h0 + whh*64 + hf*16 + l15;                                      \
    b2v[hf] = b2[hc]; wfv[hf] = wf[hc];                                      \
  }                                                                          \
  f32x4 acc[4][4];                                                           \
  _Pragma("unroll")                                                          \
  for (int i = 0; i < 4; ++i)                                                \
    _Pragma("unroll")                                                        \
    for (int j = 0; j < 4; ++j) acc[i][j] = (f32x4)0.f;                      \
  float4 aReg[4];                                                            \
  (void)aReg; (void)acw; (void)apar; (void)bl_r; (void)bl_c; (void)aBase;

#define A_LOAD(kt)                                                           \
  { _Pragma("unroll")                                                        \
    for (int j = 0; j < 4; ++j)                                              \
      aReg[j] = *(const float4*)(aBase + (size_t)(j*4)*D2c + (kt)*64); }

#define A_WRITE(buf)                                                         \
  { _Pragma("unroll")                                                        \
    for (int j = 0; j < 4; ++j){                                             \
      int r = rA + j*4;                                                      \
      uint2 pk;                                                              \
      pk.x = cvtpk(aReg[j].x, aReg[j].y);                                    \
      pk.y = cvtpk(aReg[j].z, aReg[j].w);                                    \
      *(uint2*)(As[buf] + r*64 + ((acw ^ (r & 7)) << 3) + apar) = pk; } }

#define B_GLDS(kt, buf)                                                      \
  { _Pragma("unroll")                                                        \
    for (int i = 0; i < 4; ++i){                                             \
      int g = wave*4 + i;                                                    \
      const ushort* src = w2t + (size_t)(h0 + g*8 + bl_r)*D2c                \
                          + (kt)*64 + bl_c*8;                                \
      __builtin_amdgcn_global_load_lds(                                      \
          (const __attribute__((address_space(1))) uint32_t*)src,            \
          (__attribute__((address_space(3))) uint32_t*)(Bs[buf] + g*512),    \
          16, 0, 0); } }

#define COMPUTE(buf)                                                         \
  { _Pragma("unroll")                                                        \
    for (int kk = 0; kk < 2; ++kk){                                          \
      bf16x8 af[4], bfr[4];                                                  \
      _Pragma("unroll")                                                      \
      for (int mf = 0; mf < 4; ++mf){                                        \
        int r = wm*64 + mf*16 + l15, c = kk*4 + l4;                          \
        af[mf] = *(const bf16x8*)(As[buf] + r*64 + ((c ^ (r & 7)) << 3)); }  \
      _Pragma("unroll")                                                      \
      for (int hf = 0; hf < 4; ++hf){                                        \
        int r = whh*64 + hf*16 + l15, c = kk*4 + l4;                         \
        bfr[hf] = *(const bf16x8*)(Bs[buf] + r*64 + ((c ^ (r & 7)) << 3)); } \
      _Pragma("unroll")                                                      \
      for (int mf = 0; mf < 4; ++mf)                                         \
        _Pragma("unroll")                                                    \
        for (int hf = 0; hf < 4; ++hf)                                       \
          acc[mf][hf] = __builtin_amdgcn_mfma_f32_16x16x32_bf16(             \
              af[mf], bfr[hf], acc[mf][hf], 0, 0, 0); } }

#define EPILOGUE(scoresArg)                                                  \
  { _Pragma("unroll")                                                        \
    for (int mf = 0; mf < 4; ++mf){                                          \
      _Pragma("unroll")                                                      \
      for (int r = 0; r < 4; ++r){                                           \
        int m = m0 + wm*64 + mf*16 + l4*4 + r;                               \
        int b = m / NN;                                                      \
        const float* e1 = enc1 + (size_t)b*HHc + h0 + whh*64 + l15;          \
        float s = 0.f;                                                       \
        _Pragma("unroll")                                                    \
        for (int hf = 0; hf < 4; ++hf){                                      \
          float v = acc[mf][hf][r] + b2v[hf] + e1[hf*16];                    \
          s += fmaxf(v, 0.f) * wfv[hf];                                      \
        }                                                                    \
        s += __shfl_xor(s, 1); s += __shfl_xor(s, 2);                        \
        s += __shfl_xor(s, 4); s += __shfl_xor(s, 8);                        \
        if (l15 == 0) atomicAdd(&scoresArg[m], s);                           \
      }                                                                      \
    } }

#define SB0()    __builtin_amdgcn_sched_barrier(0)
#define WAITV(n) { asm volatile("s_waitcnt vmcnt(" #n ")" ::: "memory"); SB0(); }
#define LGKM0()  { asm volatile("s_waitcnt lgkmcnt(0)" ::: "memory"); SB0(); }
#define BAR()    { SB0(); __builtin_amdgcn_s_barrier(); SB0(); }

// ---- REAL fused scores GEMM (identical to R10, feeds the pipeline) ----
__global__ __launch_bounds__(512,2) void score_gemm(
    const float*  __restrict__ in2,
    const ushort* __restrict__ w2t,
    const float*  __restrict__ b2,
    const float*  __restrict__ wf,
    const float*  __restrict__ enc1,
    float*        __restrict__ scores)
{
  GEMM_PREAMBLE(scores)
  A_LOAD(0);
  B_GLDS(0, 0);
  WAITV(4);
  A_WRITE(0);
  LGKM0();
  BAR();
  #pragma unroll 1
  for (int kt = 0; kt < 31; ++kt){
    A_LOAD(kt + 1);
    B_GLDS(kt + 1, (kt + 1) & 1);
    WAITV(8);
    BAR();
    COMPUTE(kt & 1);
    WAITV(4);
    A_WRITE((kt + 1) & 1);
    LGKM0();
    BAR();
  }
  WAITV(0);
  BAR();
  COMPUTE(1);
  EPILOGUE(scores)
}

// ---- DIAG 1: staging skeleton only (no ds_read/MFMA) ----
__global__ __launch_bounds__(512,2) void diag_stage(
    const float*  __restrict__ in2,
    const ushort* __restrict__ w2t,
    const float*  __restrict__ b2,
    const float*  __restrict__ wf,
    const float*  __restrict__ enc1,
    float*        __restrict__ scores)
{
  GEMM_PREAMBLE(scores)
  A_LOAD(0);
  B_GLDS(0, 0);
  WAITV(4);
  A_WRITE(0);
  LGKM0();
  BAR();
  #pragma unroll 1
  for (int kt = 0; kt < 31; ++kt){
    A_LOAD(kt + 1);
    B_GLDS(kt + 1, (kt + 1) & 1);
    WAITV(8);
    BAR();
    // COMPUTE removed
    WAITV(4);
    A_WRITE((kt + 1) & 1);
    LGKM0();
    BAR();
  }
  WAITV(0);
  BAR();
  // keep LDS writes live (rule #17: anti-DCE)
  ushort ka = As[0][lane], kb = Bs[0][lane];
  asm volatile("" :: "v"((uint32_t)ka), "v"((uint32_t)kb));
  EPILOGUE(scores)
}

// ---- DIAG 2: compute skeleton only (no staging / no vm waits) ----
__global__ __launch_bounds__(512,2) void diag_comp(
    const float*  __restrict__ in2,
    const ushort* __restrict__ w2t,
    const float*  __restrict__ b2,
    const float*  __restrict__ wf,
    const float*  __restrict__ enc1,
    float*        __restrict__ scores)
{
  GEMM_PREAMBLE(scores)
  BAR();
  #pragma unroll 1
  for (int kt = 0; kt < 31; ++kt){
    BAR();
    COMPUTE(kt & 1);   // reads uninitialized LDS; timing-equivalent
    LGKM0();
    BAR();
  }
  BAR();
  COMPUTE(1);
  EPILOGUE(scores)
}

// ---- DIAG 3: full work, NO barriers (per-wave counted vmcnt kept) ----
__global__ __launch_bounds__(512,2) void diag_nobar(
    const float*  __restrict__ in2,
    const ushort* __restrict__ w2t,
    const float*  __restrict__ b2,
    const float*  __restrict__ wf,
    const float*  __restrict__ enc1,
    float*        __restrict__ scores)
{
  GEMM_PREAMBLE(scores)
  A_LOAD(0);
  B_GLDS(0, 0);
  WAITV(4);
  A_WRITE(0);
  LGKM0();
  #pragma unroll 1
  for (int kt = 0; kt < 31; ++kt){
    A_LOAD(kt + 1);
    B_GLDS(kt + 1, (kt + 1) & 1);
    WAITV(8);
    COMPUTE(kt & 1);   // racy reads; timing-equivalent
    WAITV(4);
    A_WRITE((kt + 1) & 1);
    LGKM0();
  }
  WAITV(0);
  COMPUTE(1);
  EPILOGUE(scores)
}

// ---- softmax over N=196 per batch ----
__global__ __launch_bounds__(64) void softmax_kernel(const float* __restrict__ scores,
                                                     float* __restrict__ alpha){
  const int b = blockIdx.x, t = threadIdx.x;
  const float* s = scores + b*NN;
  float x[4]; float mx = -1e30f;
  #pragma unroll
  for (int i = 0; i < 4; ++i){
    int n = t + i*64;
    x[i] = (n < NN) ? s[n] : -1e30f;
    mx = fmaxf(mx, x[i]);
  }
  #pragma unroll
  for (int o = 1; o < 64; o <<= 1) mx = fmaxf(mx, __shfl_xor(mx, o));
  float sum = 0.f;
  #pragma unroll
  for (int i = 0; i < 4; ++i){
    int n = t + i*64;
    float e = (n < NN) ? __expf(x[i] - mx) : 0.f;
    x[i] = e; sum += e;
  }
  #pragma unroll
  for (int o = 1; o < 64; o <<= 1) sum += __shfl_xor(sum, o);
  float inv = 1.f / sum;
  #pragma unroll
  for (int i = 0; i < 4; ++i){
    int n = t + i*64;
    if (n < NN) alpha[b*NN + n] = x[i] * inv;
  }
}

// ---- att[b,d] = sum_n input2[b,n,d] * alpha[b,n] ----
__global__ __launch_bounds__(256) void att_kernel(const float* __restrict__ in2,
                                                  const float* __restrict__ alpha,
                                                  float* __restrict__ att){
  __shared__ float sal[NN];
  const int b = blockIdx.y;
  const int t = threadIdx.x;
  if (t < NN) sal[t] = alpha[b*NN + t];
  __syncthreads();
  const int d = blockIdx.x*256 + t;
  const float* src = in2 + (size_t)b*NN*D2c + d;
  float acc = 0.f;
  #pragma unroll 7
  for (int n = 0; n < NN; ++n)
    acc += src[(size_t)n*D2c] * sal[n];
  att[(size_t)b*D2c + d] = acc;
}

extern "C" void kernel_launch(void* const* d_in, const int* in_sizes, int n_in,
                              void* d_out, int out_size, void* d_ws, size_t ws_size,
                              hipStream_t stream){
  (void)in_sizes; (void)n_in; (void)out_size;
  const float* input1 = (const float*)d_in[0];
  const float* input2 = (const float*)d_in[1];
  const float* W1     = (const float*)d_in[2];
  const float* b1     = (const float*)d_in[3];
  const float* W2     = (const float*)d_in[4];
  const float* b2     = (const float*)d_in[5];
  const float* Wf     = (const float*)d_in[6];

  float* out   = (float*)d_out;
  float* att   = out;              // [64][2048]
  float* alpha = out + BB*D2c;     // [64][196]

  char*   ws      = (char*)d_ws;
  ushort* w2t     = (ushort*)ws;                             // 2 MiB (row-major)
  float*  enc1    = (float*)(ws + 2*1024*1024);              // 128 KiB
  float*  scores  = (float*)(ws + 2*1024*1024 + 131072);     // 50 KiB
  float*  scores2 = (float*)(ws + 2*1024*1024 + 262144);     // diag scratch 50 KiB

  hipMemsetAsync(scores, 0, MM*sizeof(float), stream);
  w2t_kernel<<<dim3(32, 8), 256, 0, stream>>>(W2, w2t);
  enc1_kernel<<<dim3(BB, 4), 128, 0, stream>>>(input1, W1, b1, enc1);
  score_gemm<<<dim3(196), 512, 0, stream>>>(input2, w2t, b2, Wf, enc1, scores);
  softmax_kernel<<<dim3(BB), 64, 0, stream>>>(scores, alpha);
  att_kernel<<<dim3(8, BB), 256, 0, stream>>>(input2, alpha, att);

  // ---- diagnostics (scratch output, never validated) ----
  if (ws_size >= 2*1024*1024 + 262144 + MM*sizeof(float)){
    diag_stage<<<dim3(196), 512, 0, stream>>>(input2, w2t, b2, Wf, enc1, scores2);
    diag_comp <<<dim3(196), 512, 0, stream>>>(input2, w2t, b2, Wf, enc1, scores2);
    diag_nobar<<<dim3(196), 512, 0, stream>>>(input2, w2t, b2, Wf, enc1, scores2);
  }
}

// Round 12
// 109.648 us; speedup vs baseline: 2.0094x; 2.0094x over previous
//
#include <hip/hip_runtime.h>
#include <hip/hip_bf16.h>
#include <stdint.h>

#define BB 64
#define NN 196
#define D1c 512
#define D2c 2048
#define HHc 512
#define MM (BB*NN)   // 12544

typedef __attribute__((ext_vector_type(8))) short bf16x8;
typedef __attribute__((ext_vector_type(4))) float f32x4;

__device__ inline ushort f2bf(float f){
  uint32_t u = __float_as_uint(f);
  u += 0x7fff + ((u >> 16) & 1);   // RNE
  return (ushort)(u >> 16);
}
__device__ inline uint32_t cvtpk(float lo, float hi){
  uint32_t r;
  asm("v_cvt_pk_bf16_f32 %0, %1, %2" : "=v"(r) : "v"(lo), "v"(hi));
  return r;
}

// ---- W2 [2048][512] f32  ->  w2t [512][2048] bf16 (row-major transposed) ----
__global__ __launch_bounds__(256) void w2t_kernel(const float* __restrict__ W2,
                                                  ushort* __restrict__ w2t){
  __shared__ float tile[64][65];
  const int kt = blockIdx.x;
  const int ht = blockIdx.y;
  const int t = threadIdx.x;
  const int tr = t >> 4;
  const int tc = (t & 15) * 4;
  #pragma unroll
  for (int p = 0; p < 4; ++p){
    int k = p*16 + tr;
    float4 v = *(const float4*)(W2 + (size_t)(kt*64 + k)*HHc + ht*64 + tc);
    tile[k][tc] = v.x; tile[k][tc+1] = v.y; tile[k][tc+2] = v.z; tile[k][tc+3] = v.w;
  }
  __syncthreads();
  #pragma unroll
  for (int p = 0; p < 4; ++p){
    int h = p*16 + tr;
    ushort4 o;
    o.x = f2bf(tile[tc  ][h]);
    o.y = f2bf(tile[tc+1][h]);
    o.z = f2bf(tile[tc+2][h]);
    o.w = f2bf(tile[tc+3][h]);
    *(ushort4*)(w2t + (size_t)(ht*64 + h)*D2c + kt*64 + tc) = o;
  }
}

// ---- enc1 = input1 @ W1 + b1   [64][512] f32 ----
__global__ __launch_bounds__(128) void enc1_kernel(const float* __restrict__ in1,
                                                   const float* __restrict__ W1,
                                                   const float* __restrict__ b1,
                                                   float* __restrict__ enc1){
  __shared__ float s1[D1c];
  const int b = blockIdx.x;
  const int ht = blockIdx.y;
  const int t = threadIdx.x;
  ((float4*)s1)[t] = ((const float4*)(in1 + (size_t)b*D1c))[t];
  __syncthreads();
  const int h = ht*128 + t;
  float acc = b1[h];
  #pragma unroll 8
  for (int d = 0; d < D1c; ++d)
    acc += s1[d] * W1[(size_t)d*HHc + h];
  enc1[b*HHc + h] = acc;
}

// ---- fused scores GEMM:  scores[m] += sum_h relu(A@W2 + b2 + enc1) * Wf ----
// tile 128m x 256h, 8 waves (2m x 4h) of 64x64, BK=64, grid 196 = 1 block/CU.
// ONE barrier per K-step (R11 ablation: 2 barriers/step serialized staging vs
// compute, 85us = 37+37+overhead; overlapped floor ~37us).
// B: depth-2 glds prefetch, triple-buffered Bs; counted vmcnt never drains the
// in-flight B(kt+2) across the barrier. A: reg-staged depth-1 (lands under
// COMPUTE). All publishes are wait-then-barrier ordered.
__global__ __launch_bounds__(512,2) void score_gemm(
    const float*  __restrict__ in2,
    const ushort* __restrict__ w2t,     // [512][2048] bf16
    const float*  __restrict__ b2,
    const float*  __restrict__ wf,
    const float*  __restrict__ enc1,    // [64][512]
    float*        __restrict__ scores)  // [12544], pre-zeroed
{
  __shared__ ushort As[2][128*64];   // [row][k], 16B-chunk XOR swizzle c^=(row&7)
  __shared__ ushort Bs[3][256*64];   // [h][k], same swizzle, triple-buffered

  const int t = threadIdx.x;
  // bijective XCD chunking for nwg=196 (q=24, r=4); h-halves of an m-panel adjacent
  const int p   = blockIdx.x;
  const int xcd = p & 7;
  const int lg  = (xcd < 4 ? xcd*25 : 100 + (xcd-4)*24) + (p >> 3);
  const int h0  = (lg & 1) * 256;
  const int m0  = (lg >> 1) * 128;

  const int wave = t >> 6, lane = t & 63;
  const int wm = wave >> 2, whh = wave & 3;   // 2m x 4h wave grid
  const int l15 = lane & 15, l4 = lane >> 4;

  // A staging: wave stages rows wave*16 + l4 + j*4; 16 lanes/row, 16B each
  const int rA = wave*16 + l4;
  const float* aBase = in2 + (size_t)(m0 + rA)*D2c + l15*4;
  const int acw  = l15 >> 1;
  const int apar = (l15 & 1) * 4;

  // B staging: wave stages rows wave*32 + i*8 + (lane>>3); pre-swizzled chunk
  const int bl_r = lane >> 3;
  const int bl_c = (lane & 7) ^ bl_r;

  f32x4 acc[4][4];
  #pragma unroll
  for (int i = 0; i < 4; ++i)
    #pragma unroll
    for (int j = 0; j < 4; ++j) acc[i][j] = (f32x4)0.f;

  float4 aReg[4];

#define A_LOAD(kt)                                                           \
  { _Pragma("unroll")                                                        \
    for (int j = 0; j < 4; ++j)                                              \
      aReg[j] = *(const float4*)(aBase + (size_t)(j*4)*D2c + (kt)*64); }

#define A_WRITE(buf)                                                         \
  { _Pragma("unroll")                                                        \
    for (int j = 0; j < 4; ++j){                                             \
      int r = rA + j*4;                                                      \
      uint2 pk;                                                              \
      pk.x = cvtpk(aReg[j].x, aReg[j].y);                                    \
      pk.y = cvtpk(aReg[j].z, aReg[j].w);                                    \
      *(uint2*)(As[buf] + r*64 + ((acw ^ (r & 7)) << 3) + apar) = pk; } }

#define B_GLDS(kt, buf)                                                      \
  { _Pragma("unroll")                                                        \
    for (int i = 0; i < 4; ++i){                                             \
      int g = wave*4 + i;                                                    \
      const ushort* src = w2t + (size_t)(h0 + g*8 + bl_r)*D2c                \
                          + (kt)*64 + bl_c*8;                                \
      __builtin_amdgcn_global_load_lds(                                      \
          (const __attribute__((address_space(1))) uint32_t*)src,            \
          (__attribute__((address_space(3))) uint32_t*)(Bs[buf] + g*512),    \
          16, 0, 0); } }

#define COMPUTE(abuf, bbuf)                                                  \
  { _Pragma("unroll")                                                        \
    for (int kk = 0; kk < 2; ++kk){                                          \
      bf16x8 af[4], bfr[4];                                                  \
      _Pragma("unroll")                                                      \
      for (int mf = 0; mf < 4; ++mf){                                        \
        int r = wm*64 + mf*16 + l15, c = kk*4 + l4;                          \
        af[mf] = *(const bf16x8*)(As[abuf] + r*64 + ((c ^ (r & 7)) << 3)); } \
      _Pragma("unroll")                                                      \
      for (int hf = 0; hf < 4; ++hf){                                        \
        int r = whh*64 + hf*16 + l15, c = kk*4 + l4;                         \
        bfr[hf] = *(const bf16x8*)(Bs[bbuf] + r*64 + ((c ^ (r & 7)) << 3)); }\
      _Pragma("unroll")                                                      \
      for (int mf = 0; mf < 4; ++mf)                                         \
        _Pragma("unroll")                                                    \
        for (int hf = 0; hf < 4; ++hf)                                       \
          acc[mf][hf] = __builtin_amdgcn_mfma_f32_16x16x32_bf16(             \
              af[mf], bfr[hf], acc[mf][hf], 0, 0, 0); } }

#define SB0()    __builtin_amdgcn_sched_barrier(0)
#define WAITV(n) { asm volatile("s_waitcnt vmcnt(" #n ")" ::: "memory"); SB0(); }
#define LGKM0()  { asm volatile("s_waitcnt lgkmcnt(0)" ::: "memory"); SB0(); }
#define BAR()    { SB0(); __builtin_amdgcn_s_barrier(); SB0(); }

  // prologue: out = [A0 4][B0 4][B1 4]
  A_LOAD(0);
  B_GLDS(0, 0);
  B_GLDS(1, 1);
  SB0();
  WAITV(8);                 // A(0) landed
  A_WRITE(0);
  WAITV(4);                 // B(0) landed (B(1) in flight)
  LGKM0();
  BAR();                    // publish As[0], Bs[0]; out = [B1]

  // steady state: enter kt with out = [B(kt+1) 4]; one barrier per step
  #pragma unroll 1
  for (int kt = 0; kt < 30; ++kt){
    A_LOAD(kt + 1);                    // out: [B(kt+1)][A(kt+1)]
    B_GLDS(kt + 2, (kt + 2) % 3);      // out: [B(kt+1)][A(kt+1)][B(kt+2)]
    SB0();                             // pin issue group above compute
    COMPUTE(kt & 1, kt % 3);           // loads land under this
    WAITV(4);                          // B(kt+1)+A(kt+1) landed; B(kt+2) flying
    A_WRITE((kt + 1) & 1);
    LGKM0();
    BAR();                             // publish As[(kt+1)&1], Bs[(kt+1)%3]
  }
  // kt = 30
  A_LOAD(31);
  SB0();
  COMPUTE(0, 0);                       // 30&1=0, 30%3=0
  WAITV(0);                            // B(31)+A(31) landed
  A_WRITE(1);
  LGKM0();
  BAR();
  COMPUTE(1, 1);                       // 31&1=1, 31%3=1

  // epilogue: relu + Wf partial over this wave's 64 h, atomic into scores
  float b2v[4], wfv[4];
  #pragma unroll
  for (int hf = 0; hf < 4; ++hf){
    int hc = h0 + whh*64 + hf*16 + l15;
    b2v[hf] = b2[hc]; wfv[hf] = wf[hc];
  }
  #pragma unroll
  for (int mf = 0; mf < 4; ++mf){
    #pragma unroll
    for (int r = 0; r < 4; ++r){
      int m = m0 + wm*64 + mf*16 + l4*4 + r;  // C/D: row=(lane>>4)*4+reg, col=lane&15
      int b = m / NN;
      const float* e1 = enc1 + (size_t)b*HHc + h0 + whh*64 + l15;
      float s = 0.f;
      #pragma unroll
      for (int hf = 0; hf < 4; ++hf){
        float v = acc[mf][hf][r] + b2v[hf] + e1[hf*16];
        s += fmaxf(v, 0.f) * wfv[hf];
      }
      s += __shfl_xor(s, 1); s += __shfl_xor(s, 2);
      s += __shfl_xor(s, 4); s += __shfl_xor(s, 8);
      if (l15 == 0) atomicAdd(&scores[m], s);
    }
  }
#undef A_LOAD
#undef A_WRITE
#undef B_GLDS
#undef COMPUTE
#undef WAITV
#undef LGKM0
#undef SB0
#undef BAR
}

// ---- softmax over N=196 per batch ----
__global__ __launch_bounds__(64) void softmax_kernel(const float* __restrict__ scores,
                                                     float* __restrict__ alpha){
  const int b = blockIdx.x, t = threadIdx.x;
  const float* s = scores + b*NN;
  float x[4]; float mx = -1e30f;
  #pragma unroll
  for (int i = 0; i < 4; ++i){
    int n = t + i*64;
    x[i] = (n < NN) ? s[n] : -1e30f;
    mx = fmaxf(mx, x[i]);
  }
  #pragma unroll
  for (int o = 1; o < 64; o <<= 1) mx = fmaxf(mx, __shfl_xor(mx, o));
  float sum = 0.f;
  #pragma unroll
  for (int i = 0; i < 4; ++i){
    int n = t + i*64;
    float e = (n < NN) ? __expf(x[i] - mx) : 0.f;
    x[i] = e; sum += e;
  }
  #pragma unroll
  for (int o = 1; o < 64; o <<= 1) sum += __shfl_xor(sum, o);
  float inv = 1.f / sum;
  #pragma unroll
  for (int i = 0; i < 4; ++i){
    int n = t + i*64;
    if (n < NN) alpha[b*NN + n] = x[i] * inv;
  }
}

// ---- att[b,d] = sum_n input2[b,n,d] * alpha[b,n] ----
__global__ __launch_bounds__(256) void att_kernel(const float* __restrict__ in2,
                                                  const float* __restrict__ alpha,
                                                  float* __restrict__ att){
  __shared__ float sal[NN];
  const int b = blockIdx.y;
  const int t = threadIdx.x;
  if (t < NN) sal[t] = alpha[b*NN + t];
  __syncthreads();
  const int d = blockIdx.x*256 + t;
  const float* src = in2 + (size_t)b*NN*D2c + d;
  float acc = 0.f;
  #pragma unroll 7
  for (int n = 0; n < NN; ++n)
    acc += src[(size_t)n*D2c] * sal[n];
  att[(size_t)b*D2c + d] = acc;
}

extern "C" void kernel_launch(void* const* d_in, const int* in_sizes, int n_in,
                              void* d_out, int out_size, void* d_ws, size_t ws_size,
                              hipStream_t stream){
  (void)in_sizes; (void)n_in; (void)out_size; (void)ws_size;
  const float* input1 = (const float*)d_in[0];
  const float* input2 = (const float*)d_in[1];
  const float* W1     = (const float*)d_in[2];
  const float* b1     = (const float*)d_in[3];
  const float* W2     = (const float*)d_in[4];
  const float* b2     = (const float*)d_in[5];
  const float* Wf     = (const float*)d_in[6];
  // d_in[7] = bf : softmax shift-invariant, provably unused.

  float* out   = (float*)d_out;
  float* att   = out;              // [64][2048]
  float* alpha = out + BB*D2c;     // [64][196]

  char*   ws     = (char*)d_ws;
  ushort* w2t    = (ushort*)ws;                              // 2 MiB (row-major)
  float*  enc1   = (float*)(ws + 2*1024*1024);               // 128 KiB
  float*  scores = (float*)(ws + 2*1024*1024 + 131072);      // 50 KiB

  hipMemsetAsync(scores, 0, MM*sizeof(float), stream);
  w2t_kernel<<<dim3(32, 8), 256, 0, stream>>>(W2, w2t);
  enc1_kernel<<<dim3(BB, 4), 128, 0, stream>>>(input1, W1, b1, enc1);
  score_gemm<<<dim3(196), 512, 0, stream>>>(input2, w2t, b2, Wf, enc1, scores);
  softmax_kernel<<<dim3(BB), 64, 0, stream>>>(scores, alpha);
  att_kernel<<<dim3(8, BB), 256, 0, stream>>>(input2, alpha, att);
}